// Round 25
// baseline (490.369 us; speedup 1.0000x reference)
//
#include <hip/hip_runtime.h>
#include <hip/hip_bf16.h>
#include <stdint.h>

typedef __bf16 bf16;
typedef __bf16 bf16x4 __attribute__((ext_vector_type(4)));
typedef __bf16 bf16x8 __attribute__((ext_vector_type(8)));
typedef float f32x4 __attribute__((ext_vector_type(4)));
typedef unsigned short ushort8 __attribute__((ext_vector_type(8)));

// ---- async global->LDS, 16B per lane. LDS dest wave-uniform base; HW adds lane*16.
__device__ __forceinline__ void gload16(const bf16* g, char* l) {
  __builtin_amdgcn_global_load_lds(
      reinterpret_cast<const __attribute__((address_space(1))) unsigned int*>(
          reinterpret_cast<uintptr_t>(g)),
      reinterpret_cast<__attribute__((address_space(3))) unsigned int*>(
          reinterpret_cast<uintptr_t>(l)),
      16, 0, 0);
}

#define VMCNT(n)  asm volatile("s_waitcnt vmcnt(" #n ")" ::: "memory")
#define LGKM0()   do { asm volatile("s_waitcnt lgkmcnt(0)" ::: "memory"); \
                       __builtin_amdgcn_sched_barrier(0); } while (0)
#define BAR()     __builtin_amdgcn_s_barrier()

// ==== merged prep: blocks [0,CAST_B) cast y/Wy/Wz to bf16; blocks [CAST_B, +2048)
// ==== do the dic pass (dicb = bf16(dic), w3t[e,k] = bf16(prior[k]*dic[k,e])).
#define CAST_B 2048
__global__ __launch_bounds__(256) void prep_all(
    const float* __restrict__ y, bf16* __restrict__ yo, int na,
    const float* __restrict__ wy, bf16* __restrict__ wyo, int nb,
    const float* __restrict__ wz, bf16* __restrict__ wzo, int nc,
    const float* __restrict__ dic, const float* __restrict__ prior,
    bf16* __restrict__ dicb, bf16* __restrict__ w3t) {
  __shared__ bf16 t[64][72];
  const int tid = threadIdx.x;
  if ((int)blockIdx.x < CAST_B) {
    int i = blockIdx.x * 256 + tid;
    const int stride = CAST_B * 256;
    const int tot = na + nb + nc;
    for (; i < tot; i += stride) {
      const float* src; bf16* dst; int j;
      if (i < na)            { src = y;  dst = yo;  j = i; }
      else if (i < na + nb)  { src = wy; dst = wyo; j = i - na; }
      else                   { src = wz; dst = wzo; j = i - na - nb; }
      const float4 v0 = reinterpret_cast<const float4*>(src)[j * 2];
      const float4 v1 = reinterpret_cast<const float4*>(src)[j * 2 + 1];
      bf16x8 o = { (bf16)v0.x, (bf16)v0.y, (bf16)v0.z, (bf16)v0.w,
                   (bf16)v1.x, (bf16)v1.y, (bf16)v1.z, (bf16)v1.w };
      reinterpret_cast<bf16x8*>(dst)[j] = o;
    }
  } else {
    const int KD = 4096, E = 2048;
    const int b2 = blockIdx.x - CAST_B;            // 0..2047
    const int k0 = (b2 & 63) * 64, e0 = (b2 >> 6) * 64;
    const int er = (tid & 15) * 4;
    const int kr = tid >> 4;
#pragma unroll
    for (int p = 0; p < 4; ++p) {
      const int k = kr + p * 16;
      const float pr = prior[k0 + k];
      const float4 v = *reinterpret_cast<const float4*>(dic + (size_t)(k0 + k) * E + e0 + er);
      bf16x4 db = { (bf16)v.x, (bf16)v.y, (bf16)v.z, (bf16)v.w };
      *reinterpret_cast<bf16x4*>(dicb + (size_t)(k0 + k) * E + e0 + er) = db;
      t[er + 0][k] = (bf16)(v.x * pr);
      t[er + 1][k] = (bf16)(v.y * pr);
      t[er + 2][k] = (bf16)(v.z * pr);
      t[er + 3][k] = (bf16)(v.w * pr);
    }
    __syncthreads();
    const int e = tid >> 2, kc = (tid & 3) * 16;
    ushort8 a = *reinterpret_cast<ushort8*>(&t[e][kc]);
    ushort8 b = *reinterpret_cast<ushort8*>(&t[e][kc + 8]);
    unsigned short* dst = (unsigned short*)w3t + (size_t)(e0 + e) * KD + k0 + kc;
    *reinterpret_cast<ushort8*>(dst) = a;
    *reinterpret_cast<ushort8*>(dst + 8) = b;
  }
}

// ---- fallback rowsum of expS: one wave per row (4096 bf16), memory-bound ----
__global__ __launch_bounds__(256) void rowsum_bf16(const unsigned short* __restrict__ S,
                                                   float* __restrict__ sums) {
  const int row = blockIdx.x * 4 + (threadIdx.x >> 6);
  const int lane = threadIdx.x & 63;
  const unsigned short* r = S + (size_t)row * 4096;
  float s = 0.f;
#pragma unroll
  for (int i = 0; i < 8; ++i) {
    ushort8 v = *reinterpret_cast<const ushort8*>(r + i * 512 + lane * 8);
#pragma unroll
    for (int j = 0; j < 8; ++j) s += __uint_as_float(((unsigned)v[j]) << 16);
  }
#pragma unroll
  for (int o = 32; o; o >>= 1) s += __shfl_xor(s, o);
  if (lane == 0) sums[row] = s;
}

// ============ 8-phase NT GEMM body, MINIMAL-BARRIER wave-slip ============
// R24 body (setprio removed from MFMA clusters: +7% verified) with the mechanism
// pushed one step: INVERTED priority -- setprio(1) while issuing ds_reads+stage
// (wants 1 slot/cycle), back to 0 before the wait+MFMA cluster (needs ~1/5
// cycles).  Read bursts drain into the LDS queue sooner -> next phase's lgkm
// completes earlier.  BN==128 path: setprio removed entirely (same mechanism).
// Barrier/staging/vmcnt ledgers identical to R19/R21 (verified).
template <int EPI, int BN>
__device__ __forceinline__ void gemm_body(
    const bf16* __restrict__ A, const bf16* __restrict__ B,
    const float* __restrict__ aux, float* __restrict__ psum,
    void* __restrict__ Cout, int M, int N, int K, float scale, int nparts,
    int orig, int nwg, char* lds) {
  constexpr int BUFSZ = 32768 + BN * 128;        // A 32KB + B
  constexpr int BOFF = 32768;
  constexpr int TM = (BN == 256) ? 128 : 64;
  constexpr int MI = TM / 16;
  constexpr int NI = 4;
  const int tid = threadIdx.x;
  const int lane = tid & 63, w = tid >> 6;

  // bijective XCD chunking (m204) over THIS problem's sub-grid, n-fast within chunk
  const int gridN = N / BN;
  int wgid;
  { const int q = nwg >> 3, r = nwg & 7, x = orig & 7, rest = orig >> 3;
    wgid = (x < r ? x * (q + 1) : r * (q + 1) + (x - r) * q) + rest; }
  const int m0 = (wgid / gridN) * 256;
  const int n0 = (wgid % gridN) * BN;

  // staging source: pre-swizzled chunk so linear LDS dest = swizzled layout
  const int srow = lane >> 3;                         // 0..7
  const int scol = ((lane & 7) ^ srow) * 8;           // chunk^row&7, elems
  const bf16* gA = A + (size_t)(m0 + w * 8 + srow) * K + scol;
  const bf16* gB = B + (size_t)(n0 + w * 8 + srow) * K + scol;

  auto stA = [&](char* dst, int u, int h) {
    gload16(gA + (size_t)(h * 128) * K + (size_t)u * 64, dst + h * 16384 + w * 1024);
    gload16(gA + (size_t)(h * 128 + 64) * K + (size_t)u * 64, dst + h * 16384 + 8192 + w * 1024);
  };
  auto stB = [&](char* dst, int u, int h) {
    gload16(gB + (size_t)(h * 128) * K + (size_t)u * 64, dst + BOFF + h * 16384 + w * 1024);
    gload16(gB + (size_t)(h * 128 + 64) * K + (size_t)u * 64, dst + BOFF + h * 16384 + 8192 + w * 1024);
  };

  // fragment read bases (swizzled)
  const int fr = lane & 15, hi = lane >> 4;
  int wm, wn;
  if constexpr (BN == 256) { wm = w >> 2; wn = w & 3; }
  else                     { wm = w >> 1; wn = w & 1; }
  const int abase = (wm * TM + fr) * 128 + ((hi ^ (fr & 7)) << 4);
  const int bbase = BOFF + (wn * 64 + fr) * 128 + ((hi ^ (fr & 7)) << 4);
#define RD_A(b, mi, ks) (*(const bf16x8*)((b) + ((abase + (mi) * 2048) ^ ((ks) << 6))))
#define RD_B(b, ni, ks) (*(const bf16x8*)((b) + ((bbase + (ni) * 2048) ^ ((ks) << 6))))

  f32x4 acc[MI][NI] = {};
  const int NT = K >> 6;

  // prologue: A(0), B(0), B(1); prove A(0)+B(0)
  stA(lds, 0, 0); stA(lds, 0, 1);
  stB(lds, 0, 0);
  if constexpr (BN == 256) stB(lds, 0, 1);
  stB(lds + BUFSZ, 1, 0);
  if constexpr (BN == 256) { stB(lds + BUFSZ, 1, 1); VMCNT(4); }
  else                     { VMCNT(2); }
  BAR();

  for (int u = 0; u < NT; ++u) {
    char* b  = lds + (size_t)(u & 1) * BUFSZ;
    char* bn = lds + (size_t)((u + 1) & 1) * BUFSZ;
    bf16x8 bb[2][NI], a[2][2];
    const bool sA = (u + 1) < NT, sB = (u + 2) < NT;

    if constexpr (BN == 256) {
      // ---- q1: B all + A(0,1); stage A-lo(u+1); lgkm0; MFMA  (no barrier) ----
      __builtin_amdgcn_s_setprio(1);   // prioritize read/stage issue
      a[0][0] = RD_A(b, 0, 0); a[0][1] = RD_A(b, 0, 1);
      a[1][0] = RD_A(b, 1, 0); a[1][1] = RD_A(b, 1, 1);
#pragma unroll
      for (int ni = 0; ni < NI; ++ni) { bb[0][ni] = RD_B(b, ni, 0); bb[1][ni] = RD_B(b, ni, 1); }
      if (sA) stA(bn, u + 1, 0);
      __builtin_amdgcn_s_setprio(0);
      LGKM0();
#pragma unroll
      for (int m2 = 0; m2 < 2; ++m2)
#pragma unroll
        for (int ni = 0; ni < NI; ++ni) {
          acc[m2][ni] = __builtin_amdgcn_mfma_f32_16x16x32_bf16(a[m2][0], bb[0][ni], acc[m2][ni], 0, 0, 0);
          acc[m2][ni] = __builtin_amdgcn_mfma_f32_16x16x32_bf16(a[m2][1], bb[1][ni], acc[m2][ni], 0, 0, 0);
        }
      // ---- q2: A(2,3); stage A-hi(u+1); lgkm0; MFMA  (no barrier) ----
      __builtin_amdgcn_s_setprio(1);
      a[0][0] = RD_A(b, 2, 0); a[0][1] = RD_A(b, 2, 1);
      a[1][0] = RD_A(b, 3, 0); a[1][1] = RD_A(b, 3, 1);
      if (sA) stA(bn, u + 1, 1);
      __builtin_amdgcn_s_setprio(0);
      LGKM0();
#pragma unroll
      for (int m2 = 0; m2 < 2; ++m2)
#pragma unroll
        for (int ni = 0; ni < NI; ++ni) {
          acc[2 + m2][ni] = __builtin_amdgcn_mfma_f32_16x16x32_bf16(a[m2][0], bb[0][ni], acc[2 + m2][ni], 0, 0, 0);
          acc[2 + m2][ni] = __builtin_amdgcn_mfma_f32_16x16x32_bf16(a[m2][1], bb[1][ni], acc[2 + m2][ni], 0, 0, 0);
        }
      // ---- q3: BAR (collectivizes q1/q2 drains); A(4,5); stage B-lo(u+2) ----
      BAR();
      __builtin_amdgcn_s_setprio(1);
      a[0][0] = RD_A(b, 4, 0); a[0][1] = RD_A(b, 4, 1);
      a[1][0] = RD_A(b, 5, 0); a[1][1] = RD_A(b, 5, 1);
      if (sB) stB(b, u + 2, 0);
      __builtin_amdgcn_s_setprio(0);
      LGKM0();
#pragma unroll
      for (int m2 = 0; m2 < 2; ++m2)
#pragma unroll
        for (int ni = 0; ni < NI; ++ni) {
          acc[4 + m2][ni] = __builtin_amdgcn_mfma_f32_16x16x32_bf16(a[m2][0], bb[0][ni], acc[4 + m2][ni], 0, 0, 0);
          acc[4 + m2][ni] = __builtin_amdgcn_mfma_f32_16x16x32_bf16(a[m2][1], bb[1][ni], acc[4 + m2][ni], 0, 0, 0);
        }
      // ---- q4: A(6,7); stage B-hi(u+2); vmcnt(4); lgkm0; MFMA; END BAR ----
      __builtin_amdgcn_s_setprio(1);
      a[0][0] = RD_A(b, 6, 0); a[0][1] = RD_A(b, 6, 1);
      a[1][0] = RD_A(b, 7, 0); a[1][1] = RD_A(b, 7, 1);
      if (sB) stB(b, u + 2, 1);
      __builtin_amdgcn_s_setprio(0);
      if (sB) VMCNT(4); else VMCNT(0);
      LGKM0();
#pragma unroll
      for (int m2 = 0; m2 < 2; ++m2)
#pragma unroll
        for (int ni = 0; ni < NI; ++ni) {
          acc[6 + m2][ni] = __builtin_amdgcn_mfma_f32_16x16x32_bf16(a[m2][0], bb[0][ni], acc[6 + m2][ni], 0, 0, 0);
          acc[6 + m2][ni] = __builtin_amdgcn_mfma_f32_16x16x32_bf16(a[m2][1], bb[1][ni], acc[6 + m2][ni], 0, 0, 0);
        }
      BAR();   // re-lockstep: collectivizes vmcnt(4) + lgkm0(q4)
    } else {
      // ---- BN==128 slip (setprio removed, R24 mechanism) ----
      a[0][0] = RD_A(b, 0, 0); a[0][1] = RD_A(b, 0, 1);
      a[1][0] = RD_A(b, 1, 0); a[1][1] = RD_A(b, 1, 1);
#pragma unroll
      for (int ni = 0; ni < NI; ++ni) { bb[0][ni] = RD_B(b, ni, 0); bb[1][ni] = RD_B(b, ni, 1); }
      if (sA) { stA(bn, u + 1, 0); stA(bn, u + 1, 1); }
      LGKM0();
#pragma unroll
      for (int m2 = 0; m2 < 2; ++m2)
#pragma unroll
        for (int ni = 0; ni < NI; ++ni) {
          acc[m2][ni] = __builtin_amdgcn_mfma_f32_16x16x32_bf16(a[m2][0], bb[0][ni], acc[m2][ni], 0, 0, 0);
          acc[m2][ni] = __builtin_amdgcn_mfma_f32_16x16x32_bf16(a[m2][1], bb[1][ni], acc[m2][ni], 0, 0, 0);
        }
      BAR();
      a[0][0] = RD_A(b, 2, 0); a[0][1] = RD_A(b, 2, 1);
      a[1][0] = RD_A(b, 3, 0); a[1][1] = RD_A(b, 3, 1);
      if (sB) stB(b, u + 2, 0);
      if (sB) VMCNT(2); else VMCNT(0);
      LGKM0();
#pragma unroll
      for (int m2 = 0; m2 < 2; ++m2)
#pragma unroll
        for (int ni = 0; ni < NI; ++ni) {
          acc[2 + m2][ni] = __builtin_amdgcn_mfma_f32_16x16x32_bf16(a[m2][0], bb[0][ni], acc[2 + m2][ni], 0, 0, 0);
          acc[2 + m2][ni] = __builtin_amdgcn_mfma_f32_16x16x32_bf16(a[m2][1], bb[1][ni], acc[2 + m2][ni], 0, 0, 0);
        }
      BAR();
    }
  }
#undef RD_A
#undef RD_B

  // ---- EPI==2: gather this block's 256 row sums (nparts partials each) ----
  float* lsum = (float*)lds;
  if constexpr (EPI == 2) {
    if (tid < 256) {
      const float* p = aux + (size_t)(m0 + tid) * nparts;
      float s = 0.f;
      for (int bp = 0; bp < nparts; ++bp) s += p[bp];
      lsum[tid] = s;
    }
    __syncthreads();
  }

  // epilogue: C/D layout col = lane&15, row = (lane>>4)*4 + j  [m89-verified]
  const int lro = hi * 4;
  if constexpr (EPI == 2) {
#pragma unroll
    for (int mi = 0; mi < MI; ++mi)
#pragma unroll
      for (int j = 0; j < 4; ++j) {
        const int lr = wm * TM + mi * 16 + lro + j;
        const float inv = 1.0f / lsum[lr];   // same-addr across fr -> LDS broadcast
        const size_t grow = (size_t)(m0 + lr) * N;
#pragma unroll
        for (int ni = 0; ni < NI; ++ni)
          ((float*)Cout)[grow + n0 + wn * 64 + ni * 16 + fr] = acc[mi][ni][j] * inv;
      }
  } else {
    float rs[MI][4];
    if constexpr (EPI == 1) {
#pragma unroll
      for (int mi = 0; mi < MI; ++mi)
#pragma unroll
        for (int j = 0; j < 4; ++j) rs[mi][j] = 0.f;
    }
#pragma unroll
    for (int ni = 0; ni < NI; ++ni) {
      const int gcol = n0 + wn * 64 + ni * 16 + fr;
      float bvs = 0.f;
      if constexpr (EPI == 0) bvs = aux[gcol];
#pragma unroll
      for (int mi = 0; mi < MI; ++mi) {
        const int grow = m0 + wm * TM + mi * 16 + lro;
#pragma unroll
        for (int j = 0; j < 4; ++j) {
          float c = acc[mi][ni][j] * scale + bvs;
          if constexpr (EPI == 1) { c = __expf(c); rs[mi][j] += c; }
          ((bf16*)Cout)[(size_t)(grow + j) * N + gcol] = (bf16)c;
        }
      }
    }
    if constexpr (EPI == 1) {
      if (psum != nullptr) {
        float* wsum = (float*)lds;   // [4 wn][256 rows] = 4 KB (post-loop, LDS dead)
        __syncthreads();             // all waves exited K-loop before LDS reuse
#pragma unroll
        for (int mi = 0; mi < MI; ++mi)
#pragma unroll
          for (int j = 0; j < 4; ++j) {
            float s = rs[mi][j];
            s += __shfl_xor(s, 1); s += __shfl_xor(s, 2);
            s += __shfl_xor(s, 4); s += __shfl_xor(s, 8);
            if (fr == 0) wsum[wn * 256 + wm * TM + mi * 16 + lro + j] = s;
          }
        __syncthreads();
        if (tid < 256) {
          const float s = wsum[tid] + wsum[256 + tid] + wsum[512 + tid] + wsum[768 + tid];
          psum[(size_t)(m0 + tid) * 16 + (n0 >> 8)] = s;
        }
      }
    }
  }
}

template <int EPI, int BN>
__global__ __launch_bounds__(512, 2) void gemm8(
    const bf16* __restrict__ A, const bf16* __restrict__ B,
    const float* __restrict__ aux, float* __restrict__ psum,
    void* __restrict__ Cout, int M, int N, int K, float scale, int nparts) {
  extern __shared__ char lds[];
  gemm_body<EPI, BN>(A, B, aux, psum, Cout, M, N, K, scale, nparts,
                     blockIdx.x, gridDim.x, lds);
}

// ---- fused independent G2+G3 in one dispatch (fills the CUs G3 alone leaves idle) ----
__global__ __launch_bounds__(512, 2) void gemm_g23(
    const bf16* __restrict__ A2, const bf16* __restrict__ B2,
    const float* __restrict__ b2, bf16* __restrict__ C2,
    const bf16* __restrict__ A3, const bf16* __restrict__ B3,
    const float* __restrict__ b3, bf16* __restrict__ C3,
    int M, int D, int E, int KD, int g2n) {
  extern __shared__ char lds[];
  if ((int)blockIdx.x < g2n)
    gemm_body<0, 256>(A2, B2, b2, nullptr, C2, M, D, D, 1.0f, 0,
                      blockIdx.x, g2n, lds);
  else
    gemm_body<0, 128>(A3, B3, b3, nullptr, C3, KD, D, E, 1.0f, 0,
                      blockIdx.x - g2n, gridDim.x - g2n, lds);
}

extern "C" void kernel_launch(void* const* d_in, const int* in_sizes, int n_in,
                              void* d_out, int out_size, void* d_ws, size_t ws_size,
                              hipStream_t stream) {
  const float* y     = (const float*)d_in[0];  // [16384,1024]
  const float* Wy_w  = (const float*)d_in[1];  // [1024,1024]
  const float* Wy_b  = (const float*)d_in[2];  // [1024]
  const float* Wz_w  = (const float*)d_in[3];  // [1024,2048]
  const float* Wz_b  = (const float*)d_in[4];  // [1024]
  const float* dic   = (const float*)d_in[5];  // [4096,2048]
  const float* prior = (const float*)d_in[6];  // [4096]
  float* z = (float*)d_out;                    // [16384,2048]

  const int M = 16384, D = 1024, E = 2048, KD = 4096;

  char* ws = (char*)d_ws;
  bf16* w3t  = (bf16*)(ws);                        // [0, 16M)
  bf16* h    = (bf16*)(ws + ((size_t)16 << 20));   // [16M, 48M)
  bf16* dzb  = (bf16*)(ws + ((size_t)48 << 20));   // [48M, 56M)
  bf16* S    = (bf16*)(ws + ((size_t)56 << 20));   // [56M, 184M)  expS after G4
  bf16* yb   = (bf16*)(ws + ((size_t)56 << 20));   // cast overlays inside S (dead pre-G4)
  bf16* Wyb  = (bf16*)(ws + ((size_t)88 << 20));
  bf16* Wzb  = (bf16*)(ws + ((size_t)90 << 20));
  bf16* dicb = (bf16*)(ws + ((size_t)94 << 20));

  // psum TAIL slab [184M, 185M): outside every live region during G4.
  const bool fused_sum = ws_size >= ((size_t)185 << 20);
  float* psum = fused_sum ? (float*)(ws + ((size_t)184 << 20)) : nullptr;
  float* sums = (float*)(ws + ((size_t)16 << 20));  // fallback: h region, dead after G4

  // 0+1) all casts + dic pass in ONE 4096-block dispatch
  prep_all<<<CAST_B + 2048, 256, 0, stream>>>(
      y, yb, M * D / 8, Wy_w, Wyb, D * D / 8, Wz_w, Wzb, D * E / 8,
      dic, prior, dicb, w3t);
  // 2+3) h = yb.Wyb^T + Wy_b  ||  dz = dicb.Wzb^T + Wz_b  (one 384-block dispatch)
  {
    const int g2n = (M / 256) * (D / 256);            // 256
    const int g3n = (KD / 256) * (D / 128);           // 128
    gemm_g23<<<g2n + g3n, 512, 131072, stream>>>(
        yb, Wyb, Wy_b, h, dicb, Wzb, Wz_b, dzb, M, D, E, KD, g2n);
  }
  // 4) expS = exp(h . dz^T / 32) -> bf16 [16384,4096] grid 1024
  gemm8<1, 256><<<(M / 256) * (KD / 256), 512, 131072, stream>>>(
      h, dzb, nullptr, psum, S, M, KD, D, 0.03125f, 0);
  if (!fused_sum) {
    rowsum_bf16<<<M / 4, 256, 0, stream>>>((const unsigned short*)S, sums);
  }
  // 5+6) z = (expS . w3t^T) / rowsum -> f32 [16384,2048]  grid 512
  gemm8<2, 256><<<(M / 256) * (E / 256), 512, 131072, stream>>>(
      S, w3t, fused_sum ? psum : sums, nullptr, z, M, E, KD, 1.0f,
      fused_sum ? 16 : 1);
}

// Round 26
// 490.100 us; speedup vs baseline: 1.0005x; 1.0005x over previous
//
#include <hip/hip_runtime.h>
#include <hip/hip_bf16.h>
#include <stdint.h>

typedef __bf16 bf16;
typedef __bf16 bf16x4 __attribute__((ext_vector_type(4)));
typedef __bf16 bf16x8 __attribute__((ext_vector_type(8)));
typedef float f32x4 __attribute__((ext_vector_type(4)));
typedef unsigned short ushort8 __attribute__((ext_vector_type(8)));

// ---- async global->LDS, 16B per lane. LDS dest wave-uniform base; HW adds lane*16.
__device__ __forceinline__ void gload16(const bf16* g, char* l) {
  __builtin_amdgcn_global_load_lds(
      reinterpret_cast<const __attribute__((address_space(1))) unsigned int*>(
          reinterpret_cast<uintptr_t>(g)),
      reinterpret_cast<__attribute__((address_space(3))) unsigned int*>(
          reinterpret_cast<uintptr_t>(l)),
      16, 0, 0);
}

#define VMCNT(n)  asm volatile("s_waitcnt vmcnt(" #n ")" ::: "memory")
#define LGKM0()   do { asm volatile("s_waitcnt lgkmcnt(0)" ::: "memory"); \
                       __builtin_amdgcn_sched_barrier(0); } while (0)
#define BAR()     __builtin_amdgcn_s_barrier()

// ==== merged prep: blocks [0,CAST_B) cast y/Wy/Wz to bf16; blocks [CAST_B, +2048)
// ==== do the dic pass (dicb = bf16(dic), w3t[e,k] = bf16(prior[k]*dic[k,e])).
#define CAST_B 2048
__global__ __launch_bounds__(256) void prep_all(
    const float* __restrict__ y, bf16* __restrict__ yo, int na,
    const float* __restrict__ wy, bf16* __restrict__ wyo, int nb,
    const float* __restrict__ wz, bf16* __restrict__ wzo, int nc,
    const float* __restrict__ dic, const float* __restrict__ prior,
    bf16* __restrict__ dicb, bf16* __restrict__ w3t) {
  __shared__ bf16 t[64][72];
  const int tid = threadIdx.x;
  if ((int)blockIdx.x < CAST_B) {
    int i = blockIdx.x * 256 + tid;
    const int stride = CAST_B * 256;
    const int tot = na + nb + nc;
    for (; i < tot; i += stride) {
      const float* src; bf16* dst; int j;
      if (i < na)            { src = y;  dst = yo;  j = i; }
      else if (i < na + nb)  { src = wy; dst = wyo; j = i - na; }
      else                   { src = wz; dst = wzo; j = i - na - nb; }
      const float4 v0 = reinterpret_cast<const float4*>(src)[j * 2];
      const float4 v1 = reinterpret_cast<const float4*>(src)[j * 2 + 1];
      bf16x8 o = { (bf16)v0.x, (bf16)v0.y, (bf16)v0.z, (bf16)v0.w,
                   (bf16)v1.x, (bf16)v1.y, (bf16)v1.z, (bf16)v1.w };
      reinterpret_cast<bf16x8*>(dst)[j] = o;
    }
  } else {
    const int KD = 4096, E = 2048;
    const int b2 = blockIdx.x - CAST_B;            // 0..2047
    const int k0 = (b2 & 63) * 64, e0 = (b2 >> 6) * 64;
    const int er = (tid & 15) * 4;
    const int kr = tid >> 4;
#pragma unroll
    for (int p = 0; p < 4; ++p) {
      const int k = kr + p * 16;
      const float pr = prior[k0 + k];
      const float4 v = *reinterpret_cast<const float4*>(dic + (size_t)(k0 + k) * E + e0 + er);
      bf16x4 db = { (bf16)v.x, (bf16)v.y, (bf16)v.z, (bf16)v.w };
      *reinterpret_cast<bf16x4*>(dicb + (size_t)(k0 + k) * E + e0 + er) = db;
      t[er + 0][k] = (bf16)(v.x * pr);
      t[er + 1][k] = (bf16)(v.y * pr);
      t[er + 2][k] = (bf16)(v.z * pr);
      t[er + 3][k] = (bf16)(v.w * pr);
    }
    __syncthreads();
    const int e = tid >> 2, kc = (tid & 3) * 16;
    ushort8 a = *reinterpret_cast<ushort8*>(&t[e][kc]);
    ushort8 b = *reinterpret_cast<ushort8*>(&t[e][kc + 8]);
    unsigned short* dst = (unsigned short*)w3t + (size_t)(e0 + e) * KD + k0 + kc;
    *reinterpret_cast<ushort8*>(dst) = a;
    *reinterpret_cast<ushort8*>(dst + 8) = b;
  }
}

// ---- fallback rowsum of expS: one wave per row (4096 bf16), memory-bound ----
__global__ __launch_bounds__(256) void rowsum_bf16(const unsigned short* __restrict__ S,
                                                   float* __restrict__ sums) {
  const int row = blockIdx.x * 4 + (threadIdx.x >> 6);
  const int lane = threadIdx.x & 63;
  const unsigned short* r = S + (size_t)row * 4096;
  float s = 0.f;
#pragma unroll
  for (int i = 0; i < 8; ++i) {
    ushort8 v = *reinterpret_cast<const ushort8*>(r + i * 512 + lane * 8);
#pragma unroll
    for (int j = 0; j < 8; ++j) s += __uint_as_float(((unsigned)v[j]) << 16);
  }
#pragma unroll
  for (int o = 32; o; o >>= 1) s += __shfl_xor(s, o);
  if (lane == 0) sums[row] = s;
}

// ====== 8-phase NT GEMM body: wave-slip + TRIPLE-BUFFERED B => ONE barrier/K-step ======
// C[M,N] = op(A[M,K].B[N,K]^T).  BM=256, BK=64, 512 thr = 8 waves.
// LDS: A dbuf 2 x 32KB @ [0,64K); B tri-buf 3 x BSZ @ [64K, 64K+3*BSZ).
//   BN=256: 64K + 96K = 160KB (CU capacity; 1 block/CU unchanged).
//   BN=128: 64K + 48K = 112KB.
// BN==256: q1 {reads B(u)+A01; stA-lo(u+1); lgkm0; MFMA}
//          q2 {reads A23; stA-hi(u+1); lgkm0; MFMA}
//          q3 {reads A45; stB-lo(u+2); lgkm0; MFMA}        <- BAR REMOVED (tri-buf)
//          q4 {reads A67; stB-hi(u+2); vmcnt(4); lgkm0; MFMA; BAR}
// RACE LEDGER (1 collective point: the end-BAR):
//  - stA(Abuf[(u+1)&1]): its A-reads (step u-1) drained by each wave's lgkm0
//    before q4-MFMA(u-1), collectivized by end-BAR(u-1).  SAFE.
//  - stB(slot (u+2)%3 == (u-1)%3): last reads q1(u-1), drained by lgkm0(q1,u-1)
//    < end-BAR(u-1); distinct from slots u%3 and (u+1)%3 being read now.  SAFE.
//  - vmcnt(4)@q4 (FIFO, 8 loads/step: 12 outstanding, newest 4 = B(u+2)) proves
//    A(u+1)+B(u+1); collectivized by end-BAR.  Unchanged from R19.
// BN==128: q1 {reads bb+a01; stA(u+1) both; lgkm0; MFMA}
//          q2 {reads a23; stB(u+2); vmcnt(2); lgkm0; MFMA; BAR}   (same ledger)
// EPI: 0 = acc*scale+aux[col] (bf16) | 1 = exp(acc*scale) (bf16; no-max softmax,
// logits |max|~3.5 << 88; + optional row partials) | 2 = acc/rowsum (f32).
template <int EPI, int BN>
__device__ __forceinline__ void gemm_body(
    const bf16* __restrict__ A, const bf16* __restrict__ B,
    const float* __restrict__ aux, float* __restrict__ psum,
    void* __restrict__ Cout, int M, int N, int K, float scale, int nparts,
    int orig, int nwg, char* lds) {
  constexpr int BSZ = BN * 128;                  // B slot bytes
  constexpr int BBASE = 65536;                   // B region start (after A dbuf)
  constexpr int TM = (BN == 256) ? 128 : 64;
  constexpr int MI = TM / 16;
  constexpr int NI = 4;
  const int tid = threadIdx.x;
  const int lane = tid & 63, w = tid >> 6;

  // bijective XCD chunking (m204) over THIS problem's sub-grid, n-fast within chunk
  const int gridN = N / BN;
  int wgid;
  { const int q = nwg >> 3, r = nwg & 7, x = orig & 7, rest = orig >> 3;
    wgid = (x < r ? x * (q + 1) : r * (q + 1) + (x - r) * q) + rest; }
  const int m0 = (wgid / gridN) * 256;
  const int n0 = (wgid % gridN) * BN;

  // staging source: pre-swizzled chunk so linear LDS dest = swizzled layout
  const int srow = lane >> 3;                         // 0..7
  const int scol = ((lane & 7) ^ srow) * 8;           // chunk^row&7, elems
  const bf16* gA = A + (size_t)(m0 + w * 8 + srow) * K + scol;
  const bf16* gB = B + (size_t)(n0 + w * 8 + srow) * K + scol;

  auto stA = [&](int u, int h) {                 // A tile u -> Abuf[u&1]
    char* dst = lds + (size_t)(u & 1) * 32768 + h * 16384;
    gload16(gA + (size_t)(h * 128) * K + (size_t)u * 64, dst + w * 1024);
    gload16(gA + (size_t)(h * 128 + 64) * K + (size_t)u * 64, dst + 8192 + w * 1024);
  };
  auto stB = [&](int u, int h) {                 // B tile u -> Bslot[u%3]
    char* dst = lds + BBASE + (size_t)(u % 3) * BSZ + h * 16384;
    gload16(gB + (size_t)(h * 128) * K + (size_t)u * 64, dst + w * 1024);
    gload16(gB + (size_t)(h * 128 + 64) * K + (size_t)u * 64, dst + 8192 + w * 1024);
  };

  // fragment read bases (swizzled)
  const int fr = lane & 15, hi = lane >> 4;
  int wm, wn;
  if constexpr (BN == 256) { wm = w >> 2; wn = w & 3; }
  else                     { wm = w >> 1; wn = w & 1; }
  const int abase = (wm * TM + fr) * 128 + ((hi ^ (fr & 7)) << 4);
  const int bbase = (wn * 64 + fr) * 128 + ((hi ^ (fr & 7)) << 4);
#define RD_A(ab, mi, ks) (*(const bf16x8*)((ab) + ((abase + (mi) * 2048) ^ ((ks) << 6))))
#define RD_B(bp, ni, ks) (*(const bf16x8*)((bp) + ((bbase + (ni) * 2048) ^ ((ks) << 6))))

  f32x4 acc[MI][NI] = {};
  const int NT = K >> 6;

  // prologue: A(0)->buf0, B(0)->slot0, B(1)->slot1; prove A(0)+B(0)
  stA(0, 0); stA(0, 1);
  if constexpr (BN == 256) {
    stB(0, 0); stB(0, 1); stB(1, 0); stB(1, 1);
    VMCNT(4);
  } else {
    stB(0, 0); stB(1, 0);
    VMCNT(2);
  }
  BAR();

  for (int u = 0; u < NT; ++u) {
    const char* ab = lds + (size_t)(u & 1) * 32768;
    const char* bp = lds + BBASE + (size_t)(u % 3) * BSZ;
    bf16x8 bb[2][NI], a[2][2];
    const bool sA = (u + 1) < NT, sB = (u + 2) < NT;

    if constexpr (BN == 256) {
      // ---- q1: B all + A(0,1); stage A-lo(u+1); lgkm0; MFMA  (no barrier) ----
      a[0][0] = RD_A(ab, 0, 0); a[0][1] = RD_A(ab, 0, 1);
      a[1][0] = RD_A(ab, 1, 0); a[1][1] = RD_A(ab, 1, 1);
#pragma unroll
      for (int ni = 0; ni < NI; ++ni) { bb[0][ni] = RD_B(bp, ni, 0); bb[1][ni] = RD_B(bp, ni, 1); }
      if (sA) stA(u + 1, 0);
      LGKM0();
#pragma unroll
      for (int m2 = 0; m2 < 2; ++m2)
#pragma unroll
        for (int ni = 0; ni < NI; ++ni) {
          acc[m2][ni] = __builtin_amdgcn_mfma_f32_16x16x32_bf16(a[m2][0], bb[0][ni], acc[m2][ni], 0, 0, 0);
          acc[m2][ni] = __builtin_amdgcn_mfma_f32_16x16x32_bf16(a[m2][1], bb[1][ni], acc[m2][ni], 0, 0, 0);
        }
      // ---- q2: A(2,3); stage A-hi(u+1); lgkm0; MFMA  (no barrier) ----
      a[0][0] = RD_A(ab, 2, 0); a[0][1] = RD_A(ab, 2, 1);
      a[1][0] = RD_A(ab, 3, 0); a[1][1] = RD_A(ab, 3, 1);
      if (sA) stA(u + 1, 1);
      LGKM0();
#pragma unroll
      for (int m2 = 0; m2 < 2; ++m2)
#pragma unroll
        for (int ni = 0; ni < NI; ++ni) {
          acc[2 + m2][ni] = __builtin_amdgcn_mfma_f32_16x16x32_bf16(a[m2][0], bb[0][ni], acc[2 + m2][ni], 0, 0, 0);
          acc[2 + m2][ni] = __builtin_amdgcn_mfma_f32_16x16x32_bf16(a[m2][1], bb[1][ni], acc[2 + m2][ni], 0, 0, 0);
        }
      // ---- q3: A(4,5); stage B-lo(u+2) [tri-buf slot: race-free]; lgkm0; MFMA ----
      a[0][0] = RD_A(ab, 4, 0); a[0][1] = RD_A(ab, 4, 1);
      a[1][0] = RD_A(ab, 5, 0); a[1][1] = RD_A(ab, 5, 1);
      if (sB) stB(u + 2, 0);
      LGKM0();
#pragma unroll
      for (int m2 = 0; m2 < 2; ++m2)
#pragma unroll
        for (int ni = 0; ni < NI; ++ni) {
          acc[4 + m2][ni] = __builtin_amdgcn_mfma_f32_16x16x32_bf16(a[m2][0], bb[0][ni], acc[4 + m2][ni], 0, 0, 0);
          acc[4 + m2][ni] = __builtin_amdgcn_mfma_f32_16x16x32_bf16(a[m2][1], bb[1][ni], acc[4 + m2][ni], 0, 0, 0);
        }
      // ---- q4: A(6,7); stage B-hi(u+2); vmcnt(4); lgkm0; MFMA; END BAR ----
      a[0][0] = RD_A(ab, 6, 0); a[0][1] = RD_A(ab, 6, 1);
      a[1][0] = RD_A(ab, 7, 0); a[1][1] = RD_A(ab, 7, 1);
      if (sB) stB(u + 2, 1);
      if (sB) VMCNT(4); else VMCNT(0);
      LGKM0();
#pragma unroll
      for (int m2 = 0; m2 < 2; ++m2)
#pragma unroll
        for (int ni = 0; ni < NI; ++ni) {
          acc[6 + m2][ni] = __builtin_amdgcn_mfma_f32_16x16x32_bf16(a[m2][0], bb[0][ni], acc[6 + m2][ni], 0, 0, 0);
          acc[6 + m2][ni] = __builtin_amdgcn_mfma_f32_16x16x32_bf16(a[m2][1], bb[1][ni], acc[6 + m2][ni], 0, 0, 0);
        }
      BAR();   // the single collective point per K-step
    } else {
      // ---- BN==128: q1 {reads; stage A(u+1); lgkm0; MFMA}  (no barrier) ----
      a[0][0] = RD_A(ab, 0, 0); a[0][1] = RD_A(ab, 0, 1);
      a[1][0] = RD_A(ab, 1, 0); a[1][1] = RD_A(ab, 1, 1);
#pragma unroll
      for (int ni = 0; ni < NI; ++ni) { bb[0][ni] = RD_B(bp, ni, 0); bb[1][ni] = RD_B(bp, ni, 1); }
      if (sA) { stA(u + 1, 0); stA(u + 1, 1); }
      LGKM0();
#pragma unroll
      for (int m2 = 0; m2 < 2; ++m2)
#pragma unroll
        for (int ni = 0; ni < NI; ++ni) {
          acc[m2][ni] = __builtin_amdgcn_mfma_f32_16x16x32_bf16(a[m2][0], bb[0][ni], acc[m2][ni], 0, 0, 0);
          acc[m2][ni] = __builtin_amdgcn_mfma_f32_16x16x32_bf16(a[m2][1], bb[1][ni], acc[m2][ni], 0, 0, 0);
        }
      // ---- q2: a23; stage B(u+2) [tri-buf]; vmcnt(2); lgkm0; MFMA; BAR ----
      a[0][0] = RD_A(ab, 2, 0); a[0][1] = RD_A(ab, 2, 1);
      a[1][0] = RD_A(ab, 3, 0); a[1][1] = RD_A(ab, 3, 1);
      if (sB) stB(u + 2, 0);
      if (sB) VMCNT(2); else VMCNT(0);
      LGKM0();
#pragma unroll
      for (int m2 = 0; m2 < 2; ++m2)
#pragma unroll
        for (int ni = 0; ni < NI; ++ni) {
          acc[2 + m2][ni] = __builtin_amdgcn_mfma_f32_16x16x32_bf16(a[m2][0], bb[0][ni], acc[2 + m2][ni], 0, 0, 0);
          acc[2 + m2][ni] = __builtin_amdgcn_mfma_f32_16x16x32_bf16(a[m2][1], bb[1][ni], acc[2 + m2][ni], 0, 0, 0);
        }
      BAR();
    }
  }
#undef RD_A
#undef RD_B

  // ---- EPI==2: gather this block's 256 row sums (nparts partials each) ----
  float* lsum = (float*)lds;
  if constexpr (EPI == 2) {
    if (tid < 256) {
      const float* p = aux + (size_t)(m0 + tid) * nparts;
      float s = 0.f;
      for (int bp2 = 0; bp2 < nparts; ++bp2) s += p[bp2];
      lsum[tid] = s;
    }
    __syncthreads();
  }

  // epilogue: C/D layout col = lane&15, row = (lane>>4)*4 + j  [m89-verified]
  const int lro = hi * 4;
  if constexpr (EPI == 2) {
#pragma unroll
    for (int mi = 0; mi < MI; ++mi)
#pragma unroll
      for (int j = 0; j < 4; ++j) {
        const int lr = wm * TM + mi * 16 + lro + j;
        const float inv = 1.0f / lsum[lr];   // same-addr across fr -> LDS broadcast
        const size_t grow = (size_t)(m0 + lr) * N;
#pragma unroll
        for (int ni = 0; ni < NI; ++ni)
          ((float*)Cout)[grow + n0 + wn * 64 + ni * 16 + fr] = acc[mi][ni][j] * inv;
      }
  } else {
    float rs[MI][4];
    if constexpr (EPI == 1) {
#pragma unroll
      for (int mi = 0; mi < MI; ++mi)
#pragma unroll
        for (int j = 0; j < 4; ++j) rs[mi][j] = 0.f;
    }
#pragma unroll
    for (int ni = 0; ni < NI; ++ni) {
      const int gcol = n0 + wn * 64 + ni * 16 + fr;
      float bvs = 0.f;
      if constexpr (EPI == 0) bvs = aux[gcol];
#pragma unroll
      for (int mi = 0; mi < MI; ++mi) {
        const int grow = m0 + wm * TM + mi * 16 + lro;
#pragma unroll
        for (int j = 0; j < 4; ++j) {
          float c = acc[mi][ni][j] * scale + bvs;
          if constexpr (EPI == 1) { c = __expf(c); rs[mi][j] += c; }
          ((bf16*)Cout)[(size_t)(grow + j) * N + gcol] = (bf16)c;
        }
      }
    }
    if constexpr (EPI == 1) {
      if (psum != nullptr) {
        float* wsum = (float*)lds;   // [4 wn][256 rows] = 4 KB (post-loop, LDS dead)
        __syncthreads();             // all waves exited K-loop before LDS reuse
#pragma unroll
        for (int mi = 0; mi < MI; ++mi)
#pragma unroll
          for (int j = 0; j < 4; ++j) {
            float s = rs[mi][j];
            s += __shfl_xor(s, 1); s += __shfl_xor(s, 2);
            s += __shfl_xor(s, 4); s += __shfl_xor(s, 8);
            if (fr == 0) wsum[wn * 256 + wm * TM + mi * 16 + lro + j] = s;
          }
        __syncthreads();
        if (tid < 256) {
          const float s = wsum[tid] + wsum[256 + tid] + wsum[512 + tid] + wsum[768 + tid];
          psum[(size_t)(m0 + tid) * 16 + (n0 >> 8)] = s;
        }
      }
    }
  }
}

template <int EPI, int BN>
__global__ __launch_bounds__(512, 2) void gemm8(
    const bf16* __restrict__ A, const bf16* __restrict__ B,
    const float* __restrict__ aux, float* __restrict__ psum,
    void* __restrict__ Cout, int M, int N, int K, float scale, int nparts) {
  extern __shared__ char lds[];
  gemm_body<EPI, BN>(A, B, aux, psum, Cout, M, N, K, scale, nparts,
                     blockIdx.x, gridDim.x, lds);
}

// ---- fused independent G2+G3 in one dispatch (fills the CUs G3 alone leaves idle) ----
__global__ __launch_bounds__(512, 2) void gemm_g23(
    const bf16* __restrict__ A2, const bf16* __restrict__ B2,
    const float* __restrict__ b2, bf16* __restrict__ C2,
    const bf16* __restrict__ A3, const bf16* __restrict__ B3,
    const float* __restrict__ b3, bf16* __restrict__ C3,
    int M, int D, int E, int KD, int g2n) {
  extern __shared__ char lds[];
  if ((int)blockIdx.x < g2n)
    gemm_body<0, 256>(A2, B2, b2, nullptr, C2, M, D, D, 1.0f, 0,
                      blockIdx.x, g2n, lds);
  else
    gemm_body<0, 128>(A3, B3, b3, nullptr, C3, KD, D, E, 1.0f, 0,
                      blockIdx.x - g2n, gridDim.x - g2n, lds);
}

extern "C" void kernel_launch(void* const* d_in, const int* in_sizes, int n_in,
                              void* d_out, int out_size, void* d_ws, size_t ws_size,
                              hipStream_t stream) {
  const float* y     = (const float*)d_in[0];  // [16384,1024]
  const float* Wy_w  = (const float*)d_in[1];  // [1024,1024]
  const float* Wy_b  = (const float*)d_in[2];  // [1024]
  const float* Wz_w  = (const float*)d_in[3];  // [1024,2048]
  const float* Wz_b  = (const float*)d_in[4];  // [1024]
  const float* dic   = (const float*)d_in[5];  // [4096,2048]
  const float* prior = (const float*)d_in[6];  // [4096]
  float* z = (float*)d_out;                    // [16384,2048]

  const int M = 16384, D = 1024, E = 2048, KD = 4096;
  const size_t LDSB = 163840;   // A dbuf 64K + B tri-buf 96K = full 160K LDS

  char* ws = (char*)d_ws;
  bf16* w3t  = (bf16*)(ws);                        // [0, 16M)
  bf16* h    = (bf16*)(ws + ((size_t)16 << 20));   // [16M, 48M)
  bf16* dzb  = (bf16*)(ws + ((size_t)48 << 20));   // [48M, 56M)
  bf16* S    = (bf16*)(ws + ((size_t)56 << 20));   // [56M, 184M)  expS after G4
  bf16* yb   = (bf16*)(ws + ((size_t)56 << 20));   // cast overlays inside S (dead pre-G4)
  bf16* Wyb  = (bf16*)(ws + ((size_t)88 << 20));
  bf16* Wzb  = (bf16*)(ws + ((size_t)90 << 20));
  bf16* dicb = (bf16*)(ws + ((size_t)94 << 20));

  // psum TAIL slab [184M, 185M): outside every live region during G4.
  const bool fused_sum = ws_size >= ((size_t)185 << 20);
  float* psum = fused_sum ? (float*)(ws + ((size_t)184 << 20)) : nullptr;
  float* sums = (float*)(ws + ((size_t)16 << 20));  // fallback: h region, dead after G4

  // 0+1) all casts + dic pass in ONE 4096-block dispatch
  prep_all<<<CAST_B + 2048, 256, 0, stream>>>(
      y, yb, M * D / 8, Wy_w, Wyb, D * D / 8, Wz_w, Wzb, D * E / 8,
      dic, prior, dicb, w3t);
  // 2+3) h = yb.Wyb^T + Wy_b  ||  dz = dicb.Wzb^T + Wz_b  (one 384-block dispatch)
  {
    const int g2n = (M / 256) * (D / 256);            // 256
    const int g3n = (KD / 256) * (D / 128);           // 128
    gemm_g23<<<g2n + g3n, 512, LDSB, stream>>>(
        yb, Wyb, Wy_b, h, dicb, Wzb, Wz_b, dzb, M, D, E, KD, g2n);
  }
  // 4) expS = exp(h . dz^T / 32) -> bf16 [16384,4096] grid 1024
  gemm8<1, 256><<<(M / 256) * (KD / 256), 512, LDSB, stream>>>(
      h, dzb, nullptr, psum, S, M, KD, D, 0.03125f, 0);
  if (!fused_sum) {
    rowsum_bf16<<<M / 4, 256, 0, stream>>>((const unsigned short*)S, sums);
  }
  // 5+6) z = (expS . w3t^T) / rowsum -> f32 [16384,2048]  grid 512
  gemm8<2, 256><<<(M / 256) * (E / 256), 512, LDSB, stream>>>(
      S, w3t, fused_sum ? psum : sums, nullptr, z, M, E, KD, 1.0f,
      fused_sum ? 16 : 1);
}